// Round 13
// baseline (156.403 us; speedup 1.0000x reference)
//
#include <hip/hip_runtime.h>
#include <hip/hip_fp16.h>

#define NBCAP 512          // max buckets (static LDS arrays)
#define BSHIFT 8           // 256 nodes per bucket
#define BSZ (1 << BSHIFT)
#define NPW 4              // nodes per wave in aggregate (processed as 2 pairs)

typedef _Float16 f16x8 __attribute__((ext_vector_type(8)));
typedef float f32x4 __attribute__((ext_vector_type(4)));

__device__ __forceinline__ __half2 shfl_xor_h2(__half2 v, int m) {
    union { __half2 h; int i; } u; u.h = v;
    u.i = __shfl_xor(u.i, m, 64);
    return u.h;
}
__device__ __forceinline__ void acc4(__half2& h0, __half2& h1, __half2& h2v, __half2& h3, uint4 v) {
    h0 = __hadd2(h0, *(const __half2*)&v.x);
    h1 = __hadd2(h1, *(const __half2*)&v.y);
    h2v = __hadd2(h2v, *(const __half2*)&v.z);
    h3 = __hadd2(h3, *(const __half2*)&v.w);
}
__device__ __forceinline__ uint4 mask4(uint4 v, unsigned m) {
    v.x &= m; v.y &= m; v.z &= m; v.w &= m; return v;
}

// ---------------- k1: partition edges by src-bucket and dst-bucket ----------------
// cursors are COUNTS (zero-initialized by memset); stage base = bucket*cap + count.
// Low-VGPR variant: only rank arrays kept in registers; src/dst re-read (L2-hot)
// in the write phase.
__global__ __launch_bounds__(256) void partition_kernel(
    const int* __restrict__ src, const int* __restrict__ dst,
    int* __restrict__ curS, int* __restrict__ curD, int cap,
    unsigned short* __restrict__ srcStage, unsigned* __restrict__ dstStage, int e)
{
    __shared__ int hS[NBCAP], hD[NBCAP], bS[NBCAP], bD[NBCAP];
    int tid = threadIdx.x;
    for (int i = tid; i < NBCAP; i += 256) { hS[i] = 0; hD[i] = 0; }
    __syncthreads();
    int blockBase = blockIdx.x * 4096;
    short rS[16], rD[16];
    #pragma unroll
    for (int k = 0; k < 16; ++k) {
        int i = blockBase + k * 256 + tid;
        if (i < e) {
            rS[k] = (short)atomicAdd(&hS[src[i] >> BSHIFT], 1);
            rD[k] = (short)atomicAdd(&hD[dst[i] >> BSHIFT], 1);
        }
    }
    __syncthreads();
    for (int i = tid; i < NBCAP; i += 256) {
        bS[i] = hS[i] ? (i * cap + atomicAdd(&curS[i], hS[i])) : 0;
        bD[i] = hD[i] ? (i * cap + atomicAdd(&curD[i], hD[i])) : 0;
    }
    __syncthreads();
    #pragma unroll
    for (int k = 0; k < 16; ++k) {
        int i = blockBase + k * 256 + tid;
        if (i < e) {
            int s = src[i], d = dst[i];
            srcStage[bS[s >> BSHIFT] + (int)rS[k]] = (unsigned short)(s & (BSZ - 1));
            dstStage[bD[d >> BSHIFT] + (int)rD[k]] =
                ((unsigned)(d & (BSZ - 1)) << 24) | (unsigned)s;
        }
    }
}

// ---------------- k2: merged per-bucket pass, 512 threads ----------------
// blocks [0,nb): din hist + CSR offsets + ndst + esrc scatter (dst buckets)
// blocks [nb,2nb): dout hist -> nsrc (src buckets)
__global__ __launch_bounds__(512) void csr_norm_kernel(
    const unsigned* __restrict__ dstStage, const unsigned short* __restrict__ srcStage,
    const int* __restrict__ curS, const int* __restrict__ curD, int cap,
    int* __restrict__ off, float* __restrict__ ndst, float* __restrict__ nsrc,
    int* __restrict__ esrc, int n, int nb, int etot)
{
    __shared__ int cnt[BSZ];
    __shared__ int pref[BSZ];
    __shared__ int scn[NBCAP];
    int b = blockIdx.x, tid = threadIdx.x;

    if (b >= nb) {
        // ---- dout_norm part ----
        b -= nb;
        int nodeBase = b << BSHIFT;
        int nloc = min(BSZ, n - nodeBase);
        if (tid < BSZ) cnt[tid] = 0;
        __syncthreads();
        int sbeg = b * cap, send = sbeg + curS[b];
        for (int e = sbeg + tid; e < send; e += 512)
            atomicAdd(&cnt[srcStage[e]], 1);
        __syncthreads();
        if (tid < nloc)
            nsrc[nodeBase + tid] = rsqrtf((float)max(cnt[tid], 1));
        return;
    }

    // ---- csr_build part ----
    // derive ebase[b] via 512-wide in-block scan of bucket counts
    int cv = (tid < nb) ? curD[tid] : 0;
    scn[tid] = cv;
    __syncthreads();
    for (int o = 1; o < NBCAP; o <<= 1) {
        int a = (tid >= o) ? scn[tid - o] : 0;
        __syncthreads();
        scn[tid] += a;
        __syncthreads();
    }
    int ebeg = scn[b] - curD[b];

    int nodeBase = b << BSHIFT;
    int nloc = min(BSZ, n - nodeBase);
    int sbeg = b * cap;
    int send = sbeg + curD[b];
    if (tid < BSZ) cnt[tid] = 0;
    __syncthreads();
    for (int e = sbeg + tid; e < send; e += 512)
        atomicAdd(&cnt[dstStage[e] >> 24], 1);
    __syncthreads();
    // 256-wide Hillis-Steele node scan (first 256 threads own one node each)
    int c = (tid < BSZ) ? cnt[tid] : 0;
    if (tid < BSZ) pref[tid] = c;
    __syncthreads();
    for (int o = 1; o < BSZ; o <<= 1) {
        int a = (tid < BSZ && tid >= o) ? pref[tid - o] : 0;
        __syncthreads();
        if (tid < BSZ) pref[tid] += a;
        __syncthreads();
    }
    if (tid < BSZ) {
        int excl = pref[tid] - c;
        if (tid < nloc) {
            off[nodeBase + tid]  = ebeg + excl;
            ndst[nodeBase + tid] = rsqrtf((float)max(c, 1));
        }
        cnt[tid] = excl;   // becomes LDS cursor
    }
    if (b == 0 && tid == 0) off[n] = etot;
    __syncthreads();
    for (int e = sbeg + tid; e < send; e += 512) {
        unsigned u = dstStage[e];
        int lp = atomicAdd(&cnt[u >> 24], 1);
        esrc[ebeg + lp] = (int)(u & 0xFFFFFFu);
    }
}

// ---------------- MFMA GEMM: T(fp16) = (nsrc*X) @ W ----------------
template<int K>
__global__ __launch_bounds__(256) void gemm_mfma_kernel(
    const float* __restrict__ X, const float* __restrict__ nsrc,
    const float* __restrict__ W, __half* __restrict__ T, int n)
{
    constexpr int KP = K + 8;
    __shared__ _Float16 sA[64 * KP];
    __shared__ _Float16 sW[64 * KP];          // W^T: [col][k]
    int tid = threadIdx.x;
    int brow = blockIdx.x * 64;

    {
        int c = tid & 63;
        int kb = (tid >> 6) * 2;
        #pragma unroll
        for (int j = 0; j < K / 8; ++j) {
            int k = kb + j * 8;
            float w0 = W[k * 64 + c], w1 = W[(k + 1) * 64 + c];
            __half2 p = __floats2half2_rn(w0, w1);
            *(unsigned*)&sW[c * KP + k] = *(unsigned*)&p;
        }
    }
    for (int i = tid; i < 64 * (K / 4); i += 256) {
        int rr = i / (K / 4);
        int kk = (i % (K / 4)) * 4;
        int row = brow + rr;
        float4 v = make_float4(0.f, 0.f, 0.f, 0.f);
        if (row < n) {
            v = ((const float4*)(X + (size_t)row * K))[kk >> 2];
            float s = nsrc[row];
            v.x *= s; v.y *= s; v.z *= s; v.w *= s;
        }
        __half2 p0 = __floats2half2_rn(v.x, v.y);
        __half2 p1 = __floats2half2_rn(v.z, v.w);
        uint2 u; u.x = *(unsigned*)&p0; u.y = *(unsigned*)&p1;
        *(uint2*)&sA[rr * KP + kk] = u;
    }
    __syncthreads();

    int l = tid & 63, wv = tid >> 6;
    int r = l & 15, g = l >> 4;
    const _Float16* aBase = sA + (wv * 16 + r) * KP + g * 8;
    const _Float16* bBase = sW + r * KP + g * 8;
    f32x4 acc0 = {0,0,0,0}, acc1 = {0,0,0,0}, acc2 = {0,0,0,0}, acc3 = {0,0,0,0};
    #pragma unroll
    for (int ks = 0; ks < K / 32; ++ks) {
        f16x8 a = *(const f16x8*)(aBase + ks * 32);
        f16x8 b0 = *(const f16x8*)(bBase + 0 * 16 * KP + ks * 32);
        f16x8 b1 = *(const f16x8*)(bBase + 1 * 16 * KP + ks * 32);
        f16x8 b2 = *(const f16x8*)(bBase + 2 * 16 * KP + ks * 32);
        f16x8 b3 = *(const f16x8*)(bBase + 3 * 16 * KP + ks * 32);
        acc0 = __builtin_amdgcn_mfma_f32_16x16x32_f16(a, b0, acc0, 0, 0, 0);
        acc1 = __builtin_amdgcn_mfma_f32_16x16x32_f16(a, b1, acc1, 0, 0, 0);
        acc2 = __builtin_amdgcn_mfma_f32_16x16x32_f16(a, b2, acc2, 0, 0, 0);
        acc3 = __builtin_amdgcn_mfma_f32_16x16x32_f16(a, b3, acc3, 0, 0, 0);
    }
    #pragma unroll
    for (int reg = 0; reg < 4; ++reg) {
        int row = brow + wv * 16 + g * 4 + reg;
        if (row < n) {
            __half* tp = T + (size_t)row * 64 + r;
            tp[0]  = __float2half(acc0[reg]);
            tp[16] = __float2half(acc1[reg]);
            tp[32] = __float2half(acc2[reg]);
            tp[48] = __float2half(acc3[reg]);
        }
    }
}

// ---------------- aggregation: out = agg(Tfp16) * ndst + b (opt relu) ----------------
// one wave per NPW nodes, processed as PAIRS. Joint main loop keeps 4 gathers
// in flight AND software-pipelines the esrc index loads: next iteration's 4
// indices are loaded between issuing the gathers and consuming them, so the
// esrc L2 latency overlaps the gather latency instead of serializing with it.
// Packed fp16 accumulate; interleaved 3-level shfl_xor reduce.
template<bool RELU>
__global__ __launch_bounds__(256) void aggregate_kernel(
    const uint4* __restrict__ T4, const int* __restrict__ off,
    const int* __restrict__ esrc, const float* __restrict__ ndst,
    const float* __restrict__ bias, float* __restrict__ out, int n)
{
    int wave = (blockIdx.x * 256 + threadIdx.x) >> 6;
    int lane = threadIdx.x & 63;
    int g = lane >> 3, f = lane & 7;
    int node0 = wave * NPW;
    if (node0 >= n) return;
    float4 bb0 = ((const float4*)bias)[f * 2];
    float4 bb1 = ((const float4*)bias)[f * 2 + 1];
    __half2 z; *(unsigned*)&z = 0u;

    for (int p = 0; p < NPW; p += 2) {
        int nA = node0 + p;
        if (nA >= n) break;
        int nB = nA + 1;
        bool hasB = nB < n;
        int begA = off[nA], endA = off[nA + 1];
        int begB = hasB ? off[nB] : 0;
        int endB = hasB ? off[nB + 1] : 0;
        __half2 a0=z,a1=z,a2=z,a3=z, b0=z,b1=z,b2=z,b3=z;
        int eA = begA, eB = begB;

        // joint main with esrc software pipeline
        bool joint = (eA + 16 <= endA) && (eB + 16 <= endB);
        int sA0, sA1, sB0, sB1;
        if (joint) {
            sA0 = esrc[eA + g]; sA1 = esrc[eA + 8 + g];
            sB0 = esrc[eB + g]; sB1 = esrc[eB + 8 + g];
        }
        while (joint) {
            uint4 vA0 = T4[(size_t)sA0 * 8 + f];
            uint4 vA1 = T4[(size_t)sA1 * 8 + f];
            uint4 vB0 = T4[(size_t)sB0 * 8 + f];
            uint4 vB1 = T4[(size_t)sB1 * 8 + f];
            eA += 16; eB += 16;
            joint = (eA + 16 <= endA) && (eB + 16 <= endB);
            if (joint) {
                sA0 = esrc[eA + g]; sA1 = esrc[eA + 8 + g];
                sB0 = esrc[eB + g]; sB1 = esrc[eB + 8 + g];
            }
            acc4(a0, a1, a2, a3, vA0);
            acc4(a0, a1, a2, a3, vA1);
            acc4(b0, b1, b2, b3, vB0);
            acc4(b0, b1, b2, b3, vB1);
        }
        // leftover mains (one node still >=16)
        while (eA + 16 <= endA) {
            int s0 = esrc[eA + g], s1 = esrc[eA + 8 + g];
            uint4 v0 = T4[(size_t)s0 * 8 + f];
            uint4 v1 = T4[(size_t)s1 * 8 + f];
            acc4(a0, a1, a2, a3, v0);
            acc4(a0, a1, a2, a3, v1);
            eA += 16;
        }
        while (eB + 16 <= endB) {
            int s0 = esrc[eB + g], s1 = esrc[eB + 8 + g];
            uint4 v0 = T4[(size_t)s0 * 8 + f];
            uint4 v1 = T4[(size_t)s1 * 8 + f];
            acc4(b0, b1, b2, b3, v0);
            acc4(b0, b1, b2, b3, v1);
            eB += 16;
        }
        // paired masked tails (<=15 each): 4 masked gathers in one chain
        if (eA < endA || eB < endB) {
            int iA0 = eA + g, iA1 = eA + 8 + g;
            int iB0 = eB + g, iB1 = eB + 8 + g;
            unsigned mA0 = iA0 < endA ? ~0u : 0u;
            unsigned mA1 = iA1 < endA ? ~0u : 0u;
            unsigned mB0 = iB0 < endB ? ~0u : 0u;
            unsigned mB1 = iB1 < endB ? ~0u : 0u;
            int cA0 = iA0 < endA ? iA0 : 0;
            int cA1 = iA1 < endA ? iA1 : 0;
            int cB0 = iB0 < endB ? iB0 : 0;
            int cB1 = iB1 < endB ? iB1 : 0;
            int sA0t = esrc[cA0], sA1t = esrc[cA1];
            int sB0t = esrc[cB0], sB1t = esrc[cB1];
            uint4 vA0 = T4[(size_t)sA0t * 8 + f];
            uint4 vA1 = T4[(size_t)sA1t * 8 + f];
            uint4 vB0 = T4[(size_t)sB0t * 8 + f];
            uint4 vB1 = T4[(size_t)sB1t * 8 + f];
            acc4(a0, a1, a2, a3, mask4(vA0, mA0));
            acc4(a0, a1, a2, a3, mask4(vA1, mA1));
            acc4(b0, b1, b2, b3, mask4(vB0, mB0));
            acc4(b0, b1, b2, b3, mask4(vB1, mB1));
        }
        // interleaved reduce trees
        #pragma unroll
        for (int m = 8; m <= 32; m <<= 1) {
            a0 = __hadd2(a0, shfl_xor_h2(a0, m));
            b0 = __hadd2(b0, shfl_xor_h2(b0, m));
            a1 = __hadd2(a1, shfl_xor_h2(a1, m));
            b1 = __hadd2(b1, shfl_xor_h2(b1, m));
            a2 = __hadd2(a2, shfl_xor_h2(a2, m));
            b2 = __hadd2(b2, shfl_xor_h2(b2, m));
            a3 = __hadd2(a3, shfl_xor_h2(a3, m));
            b3 = __hadd2(b3, shfl_xor_h2(b3, m));
        }
        if (g == 0) {
            {
                float2 f0 = __half22float2(a0), f1 = __half22float2(a1);
                float2 f2 = __half22float2(a2), f3 = __half22float2(a3);
                float nd = ndst[nA];
                float4 o0 = make_float4(f0.x * nd + bb0.x, f0.y * nd + bb0.y,
                                        f1.x * nd + bb0.z, f1.y * nd + bb0.w);
                float4 o1 = make_float4(f2.x * nd + bb1.x, f2.y * nd + bb1.y,
                                        f3.x * nd + bb1.z, f3.y * nd + bb1.w);
                if (RELU) {
                    o0.x = fmaxf(o0.x, 0.f); o0.y = fmaxf(o0.y, 0.f);
                    o0.z = fmaxf(o0.z, 0.f); o0.w = fmaxf(o0.w, 0.f);
                    o1.x = fmaxf(o1.x, 0.f); o1.y = fmaxf(o1.y, 0.f);
                    o1.z = fmaxf(o1.z, 0.f); o1.w = fmaxf(o1.w, 0.f);
                }
                ((float4*)out)[(size_t)nA * 16 + f * 2]     = o0;
                ((float4*)out)[(size_t)nA * 16 + f * 2 + 1] = o1;
            }
            if (hasB) {
                float2 f0 = __half22float2(b0), f1 = __half22float2(b1);
                float2 f2 = __half22float2(b2), f3 = __half22float2(b3);
                float nd = ndst[nB];
                float4 o0 = make_float4(f0.x * nd + bb0.x, f0.y * nd + bb0.y,
                                        f1.x * nd + bb0.z, f1.y * nd + bb0.w);
                float4 o1 = make_float4(f2.x * nd + bb1.x, f2.y * nd + bb1.y,
                                        f3.x * nd + bb1.z, f3.y * nd + bb1.w);
                if (RELU) {
                    o0.x = fmaxf(o0.x, 0.f); o0.y = fmaxf(o0.y, 0.f);
                    o0.z = fmaxf(o0.z, 0.f); o0.w = fmaxf(o0.w, 0.f);
                    o1.x = fmaxf(o1.x, 0.f); o1.y = fmaxf(o1.y, 0.f);
                    o1.z = fmaxf(o1.z, 0.f); o1.w = fmaxf(o1.w, 0.f);
                }
                ((float4*)out)[(size_t)nB * 16 + f * 2]     = o0;
                ((float4*)out)[(size_t)nB * 16 + f * 2 + 1] = o1;
            }
        }
    }
}

extern "C" void kernel_launch(void* const* d_in, const int* in_sizes, int n_in,
                              void* d_out, int out_size, void* d_ws, size_t ws_size,
                              hipStream_t stream)
{
    const float* x  = (const float*)d_in[0];
    const int*   src = (const int*)d_in[1];
    const int*   dst = (const int*)d_in[2];
    const float* W1 = (const float*)d_in[3];
    const float* b1 = (const float*)d_in[4];
    const float* W2 = (const float*)d_in[5];
    const float* b2 = (const float*)d_in[6];

    const int FIN = 128;
    const int N = in_sizes[0] / FIN;
    const int E = in_sizes[1];
    const int NB = (N + BSZ - 1) >> BSHIFT;   // 391 for N=100k (<= NBCAP=512)

    // fixed bucket capacity: avg + 2048 (>>16 sigma for random graph), 256-aligned
    int cap = ((E + NB - 1) / NB + 2048 + 255) & ~255;

    char* ws = (char*)d_ws;
    size_t o = 0;
    auto carve = [&](size_t bytes) {
        void* p = ws + o;
        o = (o + bytes + 255) & ~((size_t)255);
        return p;
    };
    int* curS   = (int*)carve(2 * NBCAP * 4);   // curS+curD adjacent: one memset
    int* curD   = curS + NBCAP;
    int* off    = (int*)carve((size_t)(N + 1) * 4);
    float* nsrc = (float*)carve((size_t)N * 4);
    float* ndst = (float*)carve((size_t)N * 4);
    int* esrc   = (int*)carve((size_t)E * 4);
    size_t tbytes  = (size_t)N * 64 * 2;                  // fp16 t
    size_t stbytes = (size_t)NB * cap * 6 + 256;          // dstStage(4B) + srcStage(2B)
    void* tstage = carve(tbytes > stbytes ? tbytes : stbytes);
    // stage buffers alias t: both fully consumed (k2) before gemm1 writes t
    __half* t = (__half*)tstage;
    unsigned* dstStage = (unsigned*)tstage;
    unsigned short* srcStage = (unsigned short*)((char*)tstage + (size_t)NB * cap * 4);

    float* h2 = (float*)d_out;
    float* h1 = (float*)d_out + (size_t)N * 64;

    int gb_e4k = (E + 4095) / 4096;
    int nwaves = (N + NPW - 1) / NPW;
    int gb_agg = (nwaves + 3) / 4;

    hipMemsetAsync(curS, 0, 2 * NBCAP * 4, stream);
    partition_kernel<<<gb_e4k, 256, 0, stream>>>(src, dst, curS, curD, cap,
                                                 srcStage, dstStage, E);
    csr_norm_kernel<<<2 * NB, 512, 0, stream>>>(dstStage, srcStage, curS, curD,
                                                cap, off, ndst, nsrc, esrc, N, NB, E);

    // layer 1: t = nsrc*(x@W1); h1 = relu(agg(t)*ndst + b1)
    gemm_mfma_kernel<128><<<(N + 63) / 64, 256, 0, stream>>>(x, nsrc, W1, t, N);
    aggregate_kernel<true><<<gb_agg, 256, 0, stream>>>((const uint4*)t, off, esrc, ndst, b1, h1, N);
    // layer 2: t = nsrc*(h1@W2); h2 = agg(t)*ndst + b2
    gemm_mfma_kernel<64><<<(N + 63) / 64, 256, 0, stream>>>(h1, nsrc, W2, t, N);
    aggregate_kernel<false><<<gb_agg, 256, 0, stream>>>((const uint4*)t, off, esrc, ndst, b2, h2, N);
}

// Round 14
// 147.249 us; speedup vs baseline: 1.0622x; 1.0622x over previous
//
#include <hip/hip_runtime.h>
#include <hip/hip_fp16.h>

#define NBCAP 512          // max buckets (static LDS arrays)
#define BSHIFT 8           // 256 nodes per bucket
#define BSZ (1 << BSHIFT)
#define NPW 4              // nodes per wave in aggregate (processed as 2 pairs)

typedef _Float16 f16x8 __attribute__((ext_vector_type(8)));
typedef float f32x4 __attribute__((ext_vector_type(4)));

__device__ __forceinline__ __half2 shfl_xor_h2(__half2 v, int m) {
    union { __half2 h; int i; } u; u.h = v;
    u.i = __shfl_xor(u.i, m, 64);
    return u.h;
}
__device__ __forceinline__ void acc4(__half2& h0, __half2& h1, __half2& h2v, __half2& h3, uint4 v) {
    h0 = __hadd2(h0, *(const __half2*)&v.x);
    h1 = __hadd2(h1, *(const __half2*)&v.y);
    h2v = __hadd2(h2v, *(const __half2*)&v.z);
    h3 = __hadd2(h3, *(const __half2*)&v.w);
}
__device__ __forceinline__ uint4 mask4(uint4 v, unsigned m) {
    v.x &= m; v.y &= m; v.z &= m; v.w &= m; return v;
}

// ---------------- k1: partition edges by src-bucket and dst-bucket ----------------
// cursors are COUNTS (zero-initialized by memset); stage base = bucket*cap + count.
// src/dst values carried in REGISTERS across phases (round-12 variant: the
// write phase must be load-free; re-reading src/dst serializes L2 latency
// into the scatter chain — measured 20 -> 45 us regression in round 13).
__global__ __launch_bounds__(256) void partition_kernel(
    const int* __restrict__ src, const int* __restrict__ dst,
    int* __restrict__ curS, int* __restrict__ curD, int cap,
    unsigned short* __restrict__ srcStage, unsigned* __restrict__ dstStage, int e)
{
    __shared__ int hS[NBCAP], hD[NBCAP], bS[NBCAP], bD[NBCAP];
    int tid = threadIdx.x;
    for (int i = tid; i < NBCAP; i += 256) { hS[i] = 0; hD[i] = 0; }
    __syncthreads();
    int blockBase = blockIdx.x * 4096;
    int s[16], d[16]; short rS[16], rD[16];
    #pragma unroll
    for (int k = 0; k < 16; ++k) {
        int i = blockBase + k * 256 + tid;
        if (i < e) {
            s[k] = src[i]; d[k] = dst[i];
            rS[k] = (short)atomicAdd(&hS[s[k] >> BSHIFT], 1);
            rD[k] = (short)atomicAdd(&hD[d[k] >> BSHIFT], 1);
        }
    }
    __syncthreads();
    for (int i = tid; i < NBCAP; i += 256) {
        bS[i] = hS[i] ? (i * cap + atomicAdd(&curS[i], hS[i])) : 0;
        bD[i] = hD[i] ? (i * cap + atomicAdd(&curD[i], hD[i])) : 0;
    }
    __syncthreads();
    #pragma unroll
    for (int k = 0; k < 16; ++k) {
        int i = blockBase + k * 256 + tid;
        if (i < e) {
            srcStage[bS[s[k] >> BSHIFT] + (int)rS[k]] = (unsigned short)(s[k] & (BSZ - 1));
            dstStage[bD[d[k] >> BSHIFT] + (int)rD[k]] =
                ((unsigned)(d[k] & (BSZ - 1)) << 24) | (unsigned)s[k];
        }
    }
}

// ---------------- k2: merged per-bucket pass, 512 threads ----------------
// blocks [0,nb): din hist + CSR offsets + ndst + esrc scatter (dst buckets)
// blocks [nb,2nb): dout hist -> nsrc (src buckets)
__global__ __launch_bounds__(512) void csr_norm_kernel(
    const unsigned* __restrict__ dstStage, const unsigned short* __restrict__ srcStage,
    const int* __restrict__ curS, const int* __restrict__ curD, int cap,
    int* __restrict__ off, float* __restrict__ ndst, float* __restrict__ nsrc,
    int* __restrict__ esrc, int n, int nb, int etot)
{
    __shared__ int cnt[BSZ];
    __shared__ int pref[BSZ];
    __shared__ int scn[NBCAP];
    int b = blockIdx.x, tid = threadIdx.x;

    if (b >= nb) {
        // ---- dout_norm part ----
        b -= nb;
        int nodeBase = b << BSHIFT;
        int nloc = min(BSZ, n - nodeBase);
        if (tid < BSZ) cnt[tid] = 0;
        __syncthreads();
        int sbeg = b * cap, send = sbeg + curS[b];
        for (int e = sbeg + tid; e < send; e += 512)
            atomicAdd(&cnt[srcStage[e]], 1);
        __syncthreads();
        if (tid < nloc)
            nsrc[nodeBase + tid] = rsqrtf((float)max(cnt[tid], 1));
        return;
    }

    // ---- csr_build part ----
    // derive ebase[b] via 512-wide in-block scan of bucket counts
    int cv = (tid < nb) ? curD[tid] : 0;
    scn[tid] = cv;
    __syncthreads();
    for (int o = 1; o < NBCAP; o <<= 1) {
        int a = (tid >= o) ? scn[tid - o] : 0;
        __syncthreads();
        scn[tid] += a;
        __syncthreads();
    }
    int ebeg = scn[b] - curD[b];

    int nodeBase = b << BSHIFT;
    int nloc = min(BSZ, n - nodeBase);
    int sbeg = b * cap;
    int send = sbeg + curD[b];
    if (tid < BSZ) cnt[tid] = 0;
    __syncthreads();
    for (int e = sbeg + tid; e < send; e += 512)
        atomicAdd(&cnt[dstStage[e] >> 24], 1);
    __syncthreads();
    // 256-wide Hillis-Steele node scan (first 256 threads own one node each)
    int c = (tid < BSZ) ? cnt[tid] : 0;
    if (tid < BSZ) pref[tid] = c;
    __syncthreads();
    for (int o = 1; o < BSZ; o <<= 1) {
        int a = (tid < BSZ && tid >= o) ? pref[tid - o] : 0;
        __syncthreads();
        if (tid < BSZ) pref[tid] += a;
        __syncthreads();
    }
    if (tid < BSZ) {
        int excl = pref[tid] - c;
        if (tid < nloc) {
            off[nodeBase + tid]  = ebeg + excl;
            ndst[nodeBase + tid] = rsqrtf((float)max(c, 1));
        }
        cnt[tid] = excl;   // becomes LDS cursor
    }
    if (b == 0 && tid == 0) off[n] = etot;
    __syncthreads();
    for (int e = sbeg + tid; e < send; e += 512) {
        unsigned u = dstStage[e];
        int lp = atomicAdd(&cnt[u >> 24], 1);
        esrc[ebeg + lp] = (int)(u & 0xFFFFFFu);
    }
}

// ---------------- MFMA GEMM: T(fp16) = (nsrc*X) @ W ----------------
template<int K>
__global__ __launch_bounds__(256) void gemm_mfma_kernel(
    const float* __restrict__ X, const float* __restrict__ nsrc,
    const float* __restrict__ W, __half* __restrict__ T, int n)
{
    constexpr int KP = K + 8;
    __shared__ _Float16 sA[64 * KP];
    __shared__ _Float16 sW[64 * KP];          // W^T: [col][k]
    int tid = threadIdx.x;
    int brow = blockIdx.x * 64;

    {
        int c = tid & 63;
        int kb = (tid >> 6) * 2;
        #pragma unroll
        for (int j = 0; j < K / 8; ++j) {
            int k = kb + j * 8;
            float w0 = W[k * 64 + c], w1 = W[(k + 1) * 64 + c];
            __half2 p = __floats2half2_rn(w0, w1);
            *(unsigned*)&sW[c * KP + k] = *(unsigned*)&p;
        }
    }
    for (int i = tid; i < 64 * (K / 4); i += 256) {
        int rr = i / (K / 4);
        int kk = (i % (K / 4)) * 4;
        int row = brow + rr;
        float4 v = make_float4(0.f, 0.f, 0.f, 0.f);
        if (row < n) {
            v = ((const float4*)(X + (size_t)row * K))[kk >> 2];
            float s = nsrc[row];
            v.x *= s; v.y *= s; v.z *= s; v.w *= s;
        }
        __half2 p0 = __floats2half2_rn(v.x, v.y);
        __half2 p1 = __floats2half2_rn(v.z, v.w);
        uint2 u; u.x = *(unsigned*)&p0; u.y = *(unsigned*)&p1;
        *(uint2*)&sA[rr * KP + kk] = u;
    }
    __syncthreads();

    int l = tid & 63, wv = tid >> 6;
    int r = l & 15, g = l >> 4;
    const _Float16* aBase = sA + (wv * 16 + r) * KP + g * 8;
    const _Float16* bBase = sW + r * KP + g * 8;
    f32x4 acc0 = {0,0,0,0}, acc1 = {0,0,0,0}, acc2 = {0,0,0,0}, acc3 = {0,0,0,0};
    #pragma unroll
    for (int ks = 0; ks < K / 32; ++ks) {
        f16x8 a = *(const f16x8*)(aBase + ks * 32);
        f16x8 b0 = *(const f16x8*)(bBase + 0 * 16 * KP + ks * 32);
        f16x8 b1 = *(const f16x8*)(bBase + 1 * 16 * KP + ks * 32);
        f16x8 b2 = *(const f16x8*)(bBase + 2 * 16 * KP + ks * 32);
        f16x8 b3 = *(const f16x8*)(bBase + 3 * 16 * KP + ks * 32);
        acc0 = __builtin_amdgcn_mfma_f32_16x16x32_f16(a, b0, acc0, 0, 0, 0);
        acc1 = __builtin_amdgcn_mfma_f32_16x16x32_f16(a, b1, acc1, 0, 0, 0);
        acc2 = __builtin_amdgcn_mfma_f32_16x16x32_f16(a, b2, acc2, 0, 0, 0);
        acc3 = __builtin_amdgcn_mfma_f32_16x16x32_f16(a, b3, acc3, 0, 0, 0);
    }
    #pragma unroll
    for (int reg = 0; reg < 4; ++reg) {
        int row = brow + wv * 16 + g * 4 + reg;
        if (row < n) {
            __half* tp = T + (size_t)row * 64 + r;
            tp[0]  = __float2half(acc0[reg]);
            tp[16] = __float2half(acc1[reg]);
            tp[32] = __float2half(acc2[reg]);
            tp[48] = __float2half(acc3[reg]);
        }
    }
}

// ---------------- aggregation: out = agg(Tfp16) * ndst + b (opt relu) ----------------
// one wave per NPW nodes, processed as PAIRS. Joint main loop keeps 4 gathers
// in flight AND software-pipelines the esrc index loads (next iteration's
// indices loaded between issuing gathers and consuming them). Packed fp16
// accumulate; interleaved 3-level shfl_xor reduce.
template<bool RELU>
__global__ __launch_bounds__(256) void aggregate_kernel(
    const uint4* __restrict__ T4, const int* __restrict__ off,
    const int* __restrict__ esrc, const float* __restrict__ ndst,
    const float* __restrict__ bias, float* __restrict__ out, int n)
{
    int wave = (blockIdx.x * 256 + threadIdx.x) >> 6;
    int lane = threadIdx.x & 63;
    int g = lane >> 3, f = lane & 7;
    int node0 = wave * NPW;
    if (node0 >= n) return;
    float4 bb0 = ((const float4*)bias)[f * 2];
    float4 bb1 = ((const float4*)bias)[f * 2 + 1];
    __half2 z; *(unsigned*)&z = 0u;

    for (int p = 0; p < NPW; p += 2) {
        int nA = node0 + p;
        if (nA >= n) break;
        int nB = nA + 1;
        bool hasB = nB < n;
        int begA = off[nA], endA = off[nA + 1];
        int begB = hasB ? off[nB] : 0;
        int endB = hasB ? off[nB + 1] : 0;
        __half2 a0=z,a1=z,a2=z,a3=z, b0=z,b1=z,b2=z,b3=z;
        int eA = begA, eB = begB;

        // joint main with esrc software pipeline
        bool joint = (eA + 16 <= endA) && (eB + 16 <= endB);
        int sA0, sA1, sB0, sB1;
        if (joint) {
            sA0 = esrc[eA + g]; sA1 = esrc[eA + 8 + g];
            sB0 = esrc[eB + g]; sB1 = esrc[eB + 8 + g];
        }
        while (joint) {
            uint4 vA0 = T4[(size_t)sA0 * 8 + f];
            uint4 vA1 = T4[(size_t)sA1 * 8 + f];
            uint4 vB0 = T4[(size_t)sB0 * 8 + f];
            uint4 vB1 = T4[(size_t)sB1 * 8 + f];
            eA += 16; eB += 16;
            joint = (eA + 16 <= endA) && (eB + 16 <= endB);
            if (joint) {
                sA0 = esrc[eA + g]; sA1 = esrc[eA + 8 + g];
                sB0 = esrc[eB + g]; sB1 = esrc[eB + 8 + g];
            }
            acc4(a0, a1, a2, a3, vA0);
            acc4(a0, a1, a2, a3, vA1);
            acc4(b0, b1, b2, b3, vB0);
            acc4(b0, b1, b2, b3, vB1);
        }
        // leftover mains (one node still >=16)
        while (eA + 16 <= endA) {
            int s0 = esrc[eA + g], s1 = esrc[eA + 8 + g];
            uint4 v0 = T4[(size_t)s0 * 8 + f];
            uint4 v1 = T4[(size_t)s1 * 8 + f];
            acc4(a0, a1, a2, a3, v0);
            acc4(a0, a1, a2, a3, v1);
            eA += 16;
        }
        while (eB + 16 <= endB) {
            int s0 = esrc[eB + g], s1 = esrc[eB + 8 + g];
            uint4 v0 = T4[(size_t)s0 * 8 + f];
            uint4 v1 = T4[(size_t)s1 * 8 + f];
            acc4(b0, b1, b2, b3, v0);
            acc4(b0, b1, b2, b3, v1);
            eB += 16;
        }
        // paired masked tails (<=15 each): 4 masked gathers in one chain
        if (eA < endA || eB < endB) {
            int iA0 = eA + g, iA1 = eA + 8 + g;
            int iB0 = eB + g, iB1 = eB + 8 + g;
            unsigned mA0 = iA0 < endA ? ~0u : 0u;
            unsigned mA1 = iA1 < endA ? ~0u : 0u;
            unsigned mB0 = iB0 < endB ? ~0u : 0u;
            unsigned mB1 = iB1 < endB ? ~0u : 0u;
            int cA0 = iA0 < endA ? iA0 : 0;
            int cA1 = iA1 < endA ? iA1 : 0;
            int cB0 = iB0 < endB ? iB0 : 0;
            int cB1 = iB1 < endB ? iB1 : 0;
            int sA0t = esrc[cA0], sA1t = esrc[cA1];
            int sB0t = esrc[cB0], sB1t = esrc[cB1];
            uint4 vA0 = T4[(size_t)sA0t * 8 + f];
            uint4 vA1 = T4[(size_t)sA1t * 8 + f];
            uint4 vB0 = T4[(size_t)sB0t * 8 + f];
            uint4 vB1 = T4[(size_t)sB1t * 8 + f];
            acc4(a0, a1, a2, a3, mask4(vA0, mA0));
            acc4(a0, a1, a2, a3, mask4(vA1, mA1));
            acc4(b0, b1, b2, b3, mask4(vB0, mB0));
            acc4(b0, b1, b2, b3, mask4(vB1, mB1));
        }
        // interleaved reduce trees
        #pragma unroll
        for (int m = 8; m <= 32; m <<= 1) {
            a0 = __hadd2(a0, shfl_xor_h2(a0, m));
            b0 = __hadd2(b0, shfl_xor_h2(b0, m));
            a1 = __hadd2(a1, shfl_xor_h2(a1, m));
            b1 = __hadd2(b1, shfl_xor_h2(b1, m));
            a2 = __hadd2(a2, shfl_xor_h2(a2, m));
            b2 = __hadd2(b2, shfl_xor_h2(b2, m));
            a3 = __hadd2(a3, shfl_xor_h2(a3, m));
            b3 = __hadd2(b3, shfl_xor_h2(b3, m));
        }
        if (g == 0) {
            {
                float2 f0 = __half22float2(a0), f1 = __half22float2(a1);
                float2 f2 = __half22float2(a2), f3 = __half22float2(a3);
                float nd = ndst[nA];
                float4 o0 = make_float4(f0.x * nd + bb0.x, f0.y * nd + bb0.y,
                                        f1.x * nd + bb0.z, f1.y * nd + bb0.w);
                float4 o1 = make_float4(f2.x * nd + bb1.x, f2.y * nd + bb1.y,
                                        f3.x * nd + bb1.z, f3.y * nd + bb1.w);
                if (RELU) {
                    o0.x = fmaxf(o0.x, 0.f); o0.y = fmaxf(o0.y, 0.f);
                    o0.z = fmaxf(o0.z, 0.f); o0.w = fmaxf(o0.w, 0.f);
                    o1.x = fmaxf(o1.x, 0.f); o1.y = fmaxf(o1.y, 0.f);
                    o1.z = fmaxf(o1.z, 0.f); o1.w = fmaxf(o1.w, 0.f);
                }
                ((float4*)out)[(size_t)nA * 16 + f * 2]     = o0;
                ((float4*)out)[(size_t)nA * 16 + f * 2 + 1] = o1;
            }
            if (hasB) {
                float2 f0 = __half22float2(b0), f1 = __half22float2(b1);
                float2 f2 = __half22float2(b2), f3 = __half22float2(b3);
                float nd = ndst[nB];
                float4 o0 = make_float4(f0.x * nd + bb0.x, f0.y * nd + bb0.y,
                                        f1.x * nd + bb0.z, f1.y * nd + bb0.w);
                float4 o1 = make_float4(f2.x * nd + bb1.x, f2.y * nd + bb1.y,
                                        f3.x * nd + bb1.z, f3.y * nd + bb1.w);
                if (RELU) {
                    o0.x = fmaxf(o0.x, 0.f); o0.y = fmaxf(o0.y, 0.f);
                    o0.z = fmaxf(o0.z, 0.f); o0.w = fmaxf(o0.w, 0.f);
                    o1.x = fmaxf(o1.x, 0.f); o1.y = fmaxf(o1.y, 0.f);
                    o1.z = fmaxf(o1.z, 0.f); o1.w = fmaxf(o1.w, 0.f);
                }
                ((float4*)out)[(size_t)nB * 16 + f * 2]     = o0;
                ((float4*)out)[(size_t)nB * 16 + f * 2 + 1] = o1;
            }
        }
    }
}

extern "C" void kernel_launch(void* const* d_in, const int* in_sizes, int n_in,
                              void* d_out, int out_size, void* d_ws, size_t ws_size,
                              hipStream_t stream)
{
    const float* x  = (const float*)d_in[0];
    const int*   src = (const int*)d_in[1];
    const int*   dst = (const int*)d_in[2];
    const float* W1 = (const float*)d_in[3];
    const float* b1 = (const float*)d_in[4];
    const float* W2 = (const float*)d_in[5];
    const float* b2 = (const float*)d_in[6];

    const int FIN = 128;
    const int N = in_sizes[0] / FIN;
    const int E = in_sizes[1];
    const int NB = (N + BSZ - 1) >> BSHIFT;   // 391 for N=100k (<= NBCAP=512)

    // fixed bucket capacity: avg + 2048 (>>16 sigma for random graph), 256-aligned
    int cap = ((E + NB - 1) / NB + 2048 + 255) & ~255;

    char* ws = (char*)d_ws;
    size_t o = 0;
    auto carve = [&](size_t bytes) {
        void* p = ws + o;
        o = (o + bytes + 255) & ~((size_t)255);
        return p;
    };
    int* curS   = (int*)carve(2 * NBCAP * 4);   // curS+curD adjacent: one memset
    int* curD   = curS + NBCAP;
    int* off    = (int*)carve((size_t)(N + 1) * 4);
    float* nsrc = (float*)carve((size_t)N * 4);
    float* ndst = (float*)carve((size_t)N * 4);
    int* esrc   = (int*)carve((size_t)E * 4);
    size_t tbytes  = (size_t)N * 64 * 2;                  // fp16 t
    size_t stbytes = (size_t)NB * cap * 6 + 256;          // dstStage(4B) + srcStage(2B)
    void* tstage = carve(tbytes > stbytes ? tbytes : stbytes);
    // stage buffers alias t: both fully consumed (k2) before gemm1 writes t
    __half* t = (__half*)tstage;
    unsigned* dstStage = (unsigned*)tstage;
    unsigned short* srcStage = (unsigned short*)((char*)tstage + (size_t)NB * cap * 4);

    float* h2 = (float*)d_out;
    float* h1 = (float*)d_out + (size_t)N * 64;

    int gb_e4k = (E + 4095) / 4096;
    int nwaves = (N + NPW - 1) / NPW;
    int gb_agg = (nwaves + 3) / 4;

    hipMemsetAsync(curS, 0, 2 * NBCAP * 4, stream);
    partition_kernel<<<gb_e4k, 256, 0, stream>>>(src, dst, curS, curD, cap,
                                                 srcStage, dstStage, E);
    csr_norm_kernel<<<2 * NB, 512, 0, stream>>>(dstStage, srcStage, curS, curD,
                                                cap, off, ndst, nsrc, esrc, N, NB, E);

    // layer 1: t = nsrc*(x@W1); h1 = relu(agg(t)*ndst + b1)
    gemm_mfma_kernel<128><<<(N + 63) / 64, 256, 0, stream>>>(x, nsrc, W1, t, N);
    aggregate_kernel<true><<<gb_agg, 256, 0, stream>>>((const uint4*)t, off, esrc, ndst, b1, h1, N);
    // layer 2: t = nsrc*(h1@W2); h2 = agg(t)*ndst + b2
    gemm_mfma_kernel<64><<<(N + 63) / 64, 256, 0, stream>>>(h1, nsrc, W2, t, N);
    aggregate_kernel<false><<<gb_agg, 256, 0, stream>>>((const uint4*)t, off, esrc, ndst, b2, h2, N);
}

// Round 15
// 143.647 us; speedup vs baseline: 1.0888x; 1.0251x over previous
//
#include <hip/hip_runtime.h>
#include <hip/hip_fp16.h>

#define NBCAP 512          // max buckets (static LDS arrays)
#define BSHIFT 8           // 256 nodes per bucket
#define BSZ (1 << BSHIFT)

typedef _Float16 f16x8 __attribute__((ext_vector_type(8)));
typedef float f32x4 __attribute__((ext_vector_type(4)));

__device__ __forceinline__ __half2 shfl_xor_h2(__half2 v, int m) {
    union { __half2 h; int i; } u; u.h = v;
    u.i = __shfl_xor(u.i, m, 64);
    return u.h;
}
__device__ __forceinline__ void acc4(__half2& h0, __half2& h1, __half2& h2v, __half2& h3, uint4 v) {
    h0 = __hadd2(h0, *(const __half2*)&v.x);
    h1 = __hadd2(h1, *(const __half2*)&v.y);
    h2v = __hadd2(h2v, *(const __half2*)&v.z);
    h3 = __hadd2(h3, *(const __half2*)&v.w);
}
__device__ __forceinline__ uint4 mask4(uint4 v, unsigned m) {
    v.x &= m; v.y &= m; v.z &= m; v.w &= m; return v;
}

// ---------------- k1: partition edges by src-bucket and dst-bucket ----------------
// cursors are COUNTS (zero-initialized by memset); stage base = bucket*cap + count.
// src/dst carried in REGISTERS across phases (write phase must be load-free:
// re-reading src/dst serializes L2 latency into the scatter chain, r13 +25us).
__global__ __launch_bounds__(256) void partition_kernel(
    const int* __restrict__ src, const int* __restrict__ dst,
    int* __restrict__ curS, int* __restrict__ curD, int cap,
    unsigned short* __restrict__ srcStage, unsigned* __restrict__ dstStage, int e)
{
    __shared__ int hS[NBCAP], hD[NBCAP], bS[NBCAP], bD[NBCAP];
    int tid = threadIdx.x;
    for (int i = tid; i < NBCAP; i += 256) { hS[i] = 0; hD[i] = 0; }
    __syncthreads();
    int blockBase = blockIdx.x * 4096;
    int s[16], d[16]; short rS[16], rD[16];
    #pragma unroll
    for (int k = 0; k < 16; ++k) {
        int i = blockBase + k * 256 + tid;
        if (i < e) {
            s[k] = src[i]; d[k] = dst[i];
            rS[k] = (short)atomicAdd(&hS[s[k] >> BSHIFT], 1);
            rD[k] = (short)atomicAdd(&hD[d[k] >> BSHIFT], 1);
        }
    }
    __syncthreads();
    for (int i = tid; i < NBCAP; i += 256) {
        bS[i] = hS[i] ? (i * cap + atomicAdd(&curS[i], hS[i])) : 0;
        bD[i] = hD[i] ? (i * cap + atomicAdd(&curD[i], hD[i])) : 0;
    }
    __syncthreads();
    #pragma unroll
    for (int k = 0; k < 16; ++k) {
        int i = blockBase + k * 256 + tid;
        if (i < e) {
            srcStage[bS[s[k] >> BSHIFT] + (int)rS[k]] = (unsigned short)(s[k] & (BSZ - 1));
            dstStage[bD[d[k] >> BSHIFT] + (int)rD[k]] =
                ((unsigned)(d[k] & (BSZ - 1)) << 24) | (unsigned)s[k];
        }
    }
}

// ---------------- k2: merged per-bucket pass, 512 threads ----------------
// blocks [0,nb): din hist + CSR offsets + ndst + esrc scatter (dst buckets)
// blocks [nb,2nb): dout hist -> nsrc (src buckets)
__global__ __launch_bounds__(512) void csr_norm_kernel(
    const unsigned* __restrict__ dstStage, const unsigned short* __restrict__ srcStage,
    const int* __restrict__ curS, const int* __restrict__ curD, int cap,
    int* __restrict__ off, float* __restrict__ ndst, float* __restrict__ nsrc,
    int* __restrict__ esrc, int n, int nb, int etot)
{
    __shared__ int cnt[BSZ];
    __shared__ int pref[BSZ];
    __shared__ int scn[NBCAP];
    int b = blockIdx.x, tid = threadIdx.x;

    if (b >= nb) {
        // ---- dout_norm part ----
        b -= nb;
        int nodeBase = b << BSHIFT;
        int nloc = min(BSZ, n - nodeBase);
        if (tid < BSZ) cnt[tid] = 0;
        __syncthreads();
        int sbeg = b * cap, send = sbeg + curS[b];
        for (int e = sbeg + tid; e < send; e += 512)
            atomicAdd(&cnt[srcStage[e]], 1);
        __syncthreads();
        if (tid < nloc)
            nsrc[nodeBase + tid] = rsqrtf((float)max(cnt[tid], 1));
        return;
    }

    // ---- csr_build part ----
    // derive ebase[b] via 512-wide in-block scan of bucket counts
    int cv = (tid < nb) ? curD[tid] : 0;
    scn[tid] = cv;
    __syncthreads();
    for (int o = 1; o < NBCAP; o <<= 1) {
        int a = (tid >= o) ? scn[tid - o] : 0;
        __syncthreads();
        scn[tid] += a;
        __syncthreads();
    }
    int ebeg = scn[b] - curD[b];

    int nodeBase = b << BSHIFT;
    int nloc = min(BSZ, n - nodeBase);
    int sbeg = b * cap;
    int send = sbeg + curD[b];
    if (tid < BSZ) cnt[tid] = 0;
    __syncthreads();
    for (int e = sbeg + tid; e < send; e += 512)
        atomicAdd(&cnt[dstStage[e] >> 24], 1);
    __syncthreads();
    // 256-wide Hillis-Steele node scan (first 256 threads own one node each)
    int c = (tid < BSZ) ? cnt[tid] : 0;
    if (tid < BSZ) pref[tid] = c;
    __syncthreads();
    for (int o = 1; o < BSZ; o <<= 1) {
        int a = (tid < BSZ && tid >= o) ? pref[tid - o] : 0;
        __syncthreads();
        if (tid < BSZ) pref[tid] += a;
        __syncthreads();
    }
    if (tid < BSZ) {
        int excl = pref[tid] - c;
        if (tid < nloc) {
            off[nodeBase + tid]  = ebeg + excl;
            ndst[nodeBase + tid] = rsqrtf((float)max(c, 1));
        }
        cnt[tid] = excl;   // becomes LDS cursor
    }
    if (b == 0 && tid == 0) off[n] = etot;
    __syncthreads();
    for (int e = sbeg + tid; e < send; e += 512) {
        unsigned u = dstStage[e];
        int lp = atomicAdd(&cnt[u >> 24], 1);
        esrc[ebeg + lp] = (int)(u & 0xFFFFFFu);
    }
}

// ---------------- MFMA GEMM: T(fp16) = (nsrc*X) @ W ----------------
template<int K>
__global__ __launch_bounds__(256) void gemm_mfma_kernel(
    const float* __restrict__ X, const float* __restrict__ nsrc,
    const float* __restrict__ W, __half* __restrict__ T, int n)
{
    constexpr int KP = K + 8;
    __shared__ _Float16 sA[64 * KP];
    __shared__ _Float16 sW[64 * KP];          // W^T: [col][k]
    int tid = threadIdx.x;
    int brow = blockIdx.x * 64;

    {
        int c = tid & 63;
        int kb = (tid >> 6) * 2;
        #pragma unroll
        for (int j = 0; j < K / 8; ++j) {
            int k = kb + j * 8;
            float w0 = W[k * 64 + c], w1 = W[(k + 1) * 64 + c];
            __half2 p = __floats2half2_rn(w0, w1);
            *(unsigned*)&sW[c * KP + k] = *(unsigned*)&p;
        }
    }
    for (int i = tid; i < 64 * (K / 4); i += 256) {
        int rr = i / (K / 4);
        int kk = (i % (K / 4)) * 4;
        int row = brow + rr;
        float4 v = make_float4(0.f, 0.f, 0.f, 0.f);
        if (row < n) {
            v = ((const float4*)(X + (size_t)row * K))[kk >> 2];
            float s = nsrc[row];
            v.x *= s; v.y *= s; v.z *= s; v.w *= s;
        }
        __half2 p0 = __floats2half2_rn(v.x, v.y);
        __half2 p1 = __floats2half2_rn(v.z, v.w);
        uint2 u; u.x = *(unsigned*)&p0; u.y = *(unsigned*)&p1;
        *(uint2*)&sA[rr * KP + kk] = u;
    }
    __syncthreads();

    int l = tid & 63, wv = tid >> 6;
    int r = l & 15, g = l >> 4;
    const _Float16* aBase = sA + (wv * 16 + r) * KP + g * 8;
    const _Float16* bBase = sW + r * KP + g * 8;
    f32x4 acc0 = {0,0,0,0}, acc1 = {0,0,0,0}, acc2 = {0,0,0,0}, acc3 = {0,0,0,0};
    #pragma unroll
    for (int ks = 0; ks < K / 32; ++ks) {
        f16x8 a = *(const f16x8*)(aBase + ks * 32);
        f16x8 b0 = *(const f16x8*)(bBase + 0 * 16 * KP + ks * 32);
        f16x8 b1 = *(const f16x8*)(bBase + 1 * 16 * KP + ks * 32);
        f16x8 b2 = *(const f16x8*)(bBase + 2 * 16 * KP + ks * 32);
        f16x8 b3 = *(const f16x8*)(bBase + 3 * 16 * KP + ks * 32);
        acc0 = __builtin_amdgcn_mfma_f32_16x16x32_f16(a, b0, acc0, 0, 0, 0);
        acc1 = __builtin_amdgcn_mfma_f32_16x16x32_f16(a, b1, acc1, 0, 0, 0);
        acc2 = __builtin_amdgcn_mfma_f32_16x16x32_f16(a, b2, acc2, 0, 0, 0);
        acc3 = __builtin_amdgcn_mfma_f32_16x16x32_f16(a, b3, acc3, 0, 0, 0);
    }
    #pragma unroll
    for (int reg = 0; reg < 4; ++reg) {
        int row = brow + wv * 16 + g * 4 + reg;
        if (row < n) {
            __half* tp = T + (size_t)row * 64 + r;
            tp[0]  = __float2half(acc0[reg]);
            tp[16] = __float2half(acc1[reg]);
            tp[32] = __float2half(acc2[reg]);
            tp[48] = __float2half(acc3[reg]);
        }
    }
}

// ---------------- aggregation: out = agg(Tfp16) * ndst + b (opt relu) ----------------
// ONE NODE PAIR PER WAVE (NPW=2): joint main loop keeps 4 independent uint4
// gathers (2 per node) in one latency chain; tails via 4 masked unconditional
// gathers covering both nodes' <=15 remainders in one chain. Pair-chains
// overlap via TLP (2x wave count) instead of serializing inside a wave.
// Packed fp16 accumulate; interleaved 3-level shfl_xor reduce.
template<bool RELU>
__global__ __launch_bounds__(256) void aggregate_kernel(
    const uint4* __restrict__ T4, const int* __restrict__ off,
    const int* __restrict__ esrc, const float* __restrict__ ndst,
    const float* __restrict__ bias, float* __restrict__ out, int n)
{
    int wave = (blockIdx.x * 256 + threadIdx.x) >> 6;
    int lane = threadIdx.x & 63;
    int g = lane >> 3, f = lane & 7;
    int nA = wave * 2;
    if (nA >= n) return;
    int nB = nA + 1;
    bool hasB = nB < n;
    float4 bb0 = ((const float4*)bias)[f * 2];
    float4 bb1 = ((const float4*)bias)[f * 2 + 1];
    __half2 z; *(unsigned*)&z = 0u;

    int begA = off[nA], endA = off[nA + 1];
    int begB = hasB ? off[nB] : 0;
    int endB = hasB ? off[nB + 1] : 0;
    __half2 a0=z,a1=z,a2=z,a3=z, b0=z,b1=z,b2=z,b3=z;
    int eA = begA, eB = begB;

    // joint main: both nodes have >=16 left -> 4 gathers in one chain
    while (eA + 16 <= endA && eB + 16 <= endB) {
        int sA0 = esrc[eA + g], sA1 = esrc[eA + 8 + g];
        int sB0 = esrc[eB + g], sB1 = esrc[eB + 8 + g];
        uint4 vA0 = T4[(size_t)sA0 * 8 + f];
        uint4 vA1 = T4[(size_t)sA1 * 8 + f];
        uint4 vB0 = T4[(size_t)sB0 * 8 + f];
        uint4 vB1 = T4[(size_t)sB1 * 8 + f];
        acc4(a0, a1, a2, a3, vA0);
        acc4(a0, a1, a2, a3, vA1);
        acc4(b0, b1, b2, b3, vB0);
        acc4(b0, b1, b2, b3, vB1);
        eA += 16; eB += 16;
    }
    // leftover mains (one node still >=16)
    while (eA + 16 <= endA) {
        int s0 = esrc[eA + g], s1 = esrc[eA + 8 + g];
        uint4 v0 = T4[(size_t)s0 * 8 + f];
        uint4 v1 = T4[(size_t)s1 * 8 + f];
        acc4(a0, a1, a2, a3, v0);
        acc4(a0, a1, a2, a3, v1);
        eA += 16;
    }
    while (eB + 16 <= endB) {
        int s0 = esrc[eB + g], s1 = esrc[eB + 8 + g];
        uint4 v0 = T4[(size_t)s0 * 8 + f];
        uint4 v1 = T4[(size_t)s1 * 8 + f];
        acc4(b0, b1, b2, b3, v0);
        acc4(b0, b1, b2, b3, v1);
        eB += 16;
    }
    // paired masked tails (<=15 each): 4 masked gathers in one chain
    if (eA < endA || eB < endB) {
        int iA0 = eA + g, iA1 = eA + 8 + g;
        int iB0 = eB + g, iB1 = eB + 8 + g;
        unsigned mA0 = iA0 < endA ? ~0u : 0u;
        unsigned mA1 = iA1 < endA ? ~0u : 0u;
        unsigned mB0 = iB0 < endB ? ~0u : 0u;
        unsigned mB1 = iB1 < endB ? ~0u : 0u;
        int cA0 = iA0 < endA ? iA0 : 0;
        int cA1 = iA1 < endA ? iA1 : 0;
        int cB0 = iB0 < endB ? iB0 : 0;
        int cB1 = iB1 < endB ? iB1 : 0;
        int sA0 = esrc[cA0], sA1 = esrc[cA1];
        int sB0 = esrc[cB0], sB1 = esrc[cB1];
        uint4 vA0 = T4[(size_t)sA0 * 8 + f];
        uint4 vA1 = T4[(size_t)sA1 * 8 + f];
        uint4 vB0 = T4[(size_t)sB0 * 8 + f];
        uint4 vB1 = T4[(size_t)sB1 * 8 + f];
        acc4(a0, a1, a2, a3, mask4(vA0, mA0));
        acc4(a0, a1, a2, a3, mask4(vA1, mA1));
        acc4(b0, b1, b2, b3, mask4(vB0, mB0));
        acc4(b0, b1, b2, b3, mask4(vB1, mB1));
    }
    // interleaved reduce trees
    #pragma unroll
    for (int m = 8; m <= 32; m <<= 1) {
        a0 = __hadd2(a0, shfl_xor_h2(a0, m));
        b0 = __hadd2(b0, shfl_xor_h2(b0, m));
        a1 = __hadd2(a1, shfl_xor_h2(a1, m));
        b1 = __hadd2(b1, shfl_xor_h2(b1, m));
        a2 = __hadd2(a2, shfl_xor_h2(a2, m));
        b2 = __hadd2(b2, shfl_xor_h2(b2, m));
        a3 = __hadd2(a3, shfl_xor_h2(a3, m));
        b3 = __hadd2(b3, shfl_xor_h2(b3, m));
    }
    if (g == 0) {
        {
            float2 f0 = __half22float2(a0), f1 = __half22float2(a1);
            float2 f2 = __half22float2(a2), f3 = __half22float2(a3);
            float nd = ndst[nA];
            float4 o0 = make_float4(f0.x * nd + bb0.x, f0.y * nd + bb0.y,
                                    f1.x * nd + bb0.z, f1.y * nd + bb0.w);
            float4 o1 = make_float4(f2.x * nd + bb1.x, f2.y * nd + bb1.y,
                                    f3.x * nd + bb1.z, f3.y * nd + bb1.w);
            if (RELU) {
                o0.x = fmaxf(o0.x, 0.f); o0.y = fmaxf(o0.y, 0.f);
                o0.z = fmaxf(o0.z, 0.f); o0.w = fmaxf(o0.w, 0.f);
                o1.x = fmaxf(o1.x, 0.f); o1.y = fmaxf(o1.y, 0.f);
                o1.z = fmaxf(o1.z, 0.f); o1.w = fmaxf(o1.w, 0.f);
            }
            ((float4*)out)[(size_t)nA * 16 + f * 2]     = o0;
            ((float4*)out)[(size_t)nA * 16 + f * 2 + 1] = o1;
        }
        if (hasB) {
            float2 f0 = __half22float2(b0), f1 = __half22float2(b1);
            float2 f2 = __half22float2(b2), f3 = __half22float2(b3);
            float nd = ndst[nB];
            float4 o0 = make_float4(f0.x * nd + bb0.x, f0.y * nd + bb0.y,
                                    f1.x * nd + bb0.z, f1.y * nd + bb0.w);
            float4 o1 = make_float4(f2.x * nd + bb1.x, f2.y * nd + bb1.y,
                                    f3.x * nd + bb1.z, f3.y * nd + bb1.w);
            if (RELU) {
                o0.x = fmaxf(o0.x, 0.f); o0.y = fmaxf(o0.y, 0.f);
                o0.z = fmaxf(o0.z, 0.f); o0.w = fmaxf(o0.w, 0.f);
                o1.x = fmaxf(o1.x, 0.f); o1.y = fmaxf(o1.y, 0.f);
                o1.z = fmaxf(o1.z, 0.f); o1.w = fmaxf(o1.w, 0.f);
            }
            ((float4*)out)[(size_t)nB * 16 + f * 2]     = o0;
            ((float4*)out)[(size_t)nB * 16 + f * 2 + 1] = o1;
        }
    }
}

extern "C" void kernel_launch(void* const* d_in, const int* in_sizes, int n_in,
                              void* d_out, int out_size, void* d_ws, size_t ws_size,
                              hipStream_t stream)
{
    const float* x  = (const float*)d_in[0];
    const int*   src = (const int*)d_in[1];
    const int*   dst = (const int*)d_in[2];
    const float* W1 = (const float*)d_in[3];
    const float* b1 = (const float*)d_in[4];
    const float* W2 = (const float*)d_in[5];
    const float* b2 = (const float*)d_in[6];

    const int FIN = 128;
    const int N = in_sizes[0] / FIN;
    const int E = in_sizes[1];
    const int NB = (N + BSZ - 1) >> BSHIFT;   // 391 for N=100k (<= NBCAP=512)

    // fixed bucket capacity: avg + 2048 (>>16 sigma for random graph), 256-aligned
    int cap = ((E + NB - 1) / NB + 2048 + 255) & ~255;

    char* ws = (char*)d_ws;
    size_t o = 0;
    auto carve = [&](size_t bytes) {
        void* p = ws + o;
        o = (o + bytes + 255) & ~((size_t)255);
        return p;
    };
    int* curS   = (int*)carve(2 * NBCAP * 4);   // curS+curD adjacent: one memset
    int* curD   = curS + NBCAP;
    int* off    = (int*)carve((size_t)(N + 1) * 4);
    float* nsrc = (float*)carve((size_t)N * 4);
    float* ndst = (float*)carve((size_t)N * 4);
    int* esrc   = (int*)carve((size_t)E * 4);
    size_t tbytes  = (size_t)N * 64 * 2;                  // fp16 t
    size_t stbytes = (size_t)NB * cap * 6 + 256;          // dstStage(4B) + srcStage(2B)
    void* tstage = carve(tbytes > stbytes ? tbytes : stbytes);
    // stage buffers alias t: both fully consumed (k2) before gemm1 writes t
    __half* t = (__half*)tstage;
    unsigned* dstStage = (unsigned*)tstage;
    unsigned short* srcStage = (unsigned short*)((char*)tstage + (size_t)NB * cap * 4);

    float* h2 = (float*)d_out;
    float* h1 = (float*)d_out + (size_t)N * 64;

    int gb_e4k = (E + 4095) / 4096;
    int nwaves = (N + 1) / 2;
    int gb_agg = (nwaves + 3) / 4;

    hipMemsetAsync(curS, 0, 2 * NBCAP * 4, stream);
    partition_kernel<<<gb_e4k, 256, 0, stream>>>(src, dst, curS, curD, cap,
                                                 srcStage, dstStage, E);
    csr_norm_kernel<<<2 * NB, 512, 0, stream>>>(dstStage, srcStage, curS, curD,
                                                cap, off, ndst, nsrc, esrc, N, NB, E);

    // layer 1: t = nsrc*(x@W1); h1 = relu(agg(t)*ndst + b1)
    gemm_mfma_kernel<128><<<(N + 63) / 64, 256, 0, stream>>>(x, nsrc, W1, t, N);
    aggregate_kernel<true><<<gb_agg, 256, 0, stream>>>((const uint4*)t, off, esrc, ndst, b1, h1, N);
    // layer 2: t = nsrc*(h1@W2); h2 = agg(t)*ndst + b2
    gemm_mfma_kernel<64><<<(N + 63) / 64, 256, 0, stream>>>(h1, nsrc, W2, t, N);
    aggregate_kernel<false><<<gb_agg, 256, 0, stream>>>((const uint4*)t, off, esrc, ndst, b2, h2, N);
}